// Round 6
// baseline (139.824 us; speedup 1.0000x reference)
//
#include <hip/hip_runtime.h>

// CRF forward logZ. Inputs: words i32 [2048][256], ThetaB f32 [64][128],
// WA f32 [64][64], E f32 [50002][128]. out: f32 [2048].
// ws: Btb bf16 emission table, permuted layout [w][q][kc] uint2 = 6.4 MB.
//
// R6: Btb layout gives each fwdbwd lane its 32 B of emissions CONTIGUOUS ->
// 2x global_load_dwordx4 per step (was 4 scattered uint2). Goal: keep the
// 6-deep prefetch ring in VGPRs (R5: AGPR demotion forced immediate waitcnt
// after issue -> ~900 cyc of gather latency exposed per step).

#define NROWS 50002
#define EOS_T 62
#define BOS_T 63
#define TLEN  256
#define LOG64 4.1588830833596715f

typedef __attribute__((ext_vector_type(4))) short bf16x4;
typedef __attribute__((ext_vector_type(8))) short bf16x8;
typedef __attribute__((ext_vector_type(4))) float f32x4;

// round-half-up f32->bf16 pair pack (2 add + 1 perm); lo in low 16 bits
static __device__ __forceinline__ unsigned pack_bf2(float lo, float hi) {
    unsigned a = __float_as_uint(lo) + 0x8000u;
    unsigned b = __float_as_uint(hi) + 0x8000u;
    return __builtin_amdgcn_perm(b, a, 0x07060302u);
}
static __device__ __forceinline__ bf16x8 pack8(float4 a, float4 b) {
    union { bf16x8 v; unsigned u[4]; } r;
    r.u[0] = pack_bf2(a.x, a.y); r.u[1] = pack_bf2(a.z, a.w);
    r.u[2] = pack_bf2(b.x, b.y); r.u[3] = pack_bf2(b.z, b.w);
    return r.v;
}
static __device__ __forceinline__ bf16x4 pack4(float f0, float f1, float f2, float f3) {
    union { bf16x4 v; unsigned u[2]; } r;
    r.u[0] = pack_bf2(f0, f1); r.u[1] = pack_bf2(f2, f3);
    return r.v;
}

// Btb index: word w, lane-quad q, tag chunk kc -> tags kc*16 + q*4 + {0..3}
// (uint2 units). Contiguous in kc => one lane's step-read is 32 B contiguous.
#define BIDX(w, q, kc) ((size_t)(w) * 16 + (q) * 4 + (kc))

// ---------------------------------------------------------------------------
// Kernel 1: Btb = bf16(exp(ThetaB . E^T)); tags 62,63 -> 0.
// MFMA GEMM. 2 waves/block x 2 row-tiles (782 blocks -> ~6 waves/CU).
// B-fragments for tile it+1 prefetched before tile it's MFMAs.
// ---------------------------------------------------------------------------
__global__ __launch_bounds__(128, 1) void emis_mfma(
    const float* __restrict__ ThetaB, const float* __restrict__ E,
    uint2* __restrict__ Btb)
{
    const int lane = threadIdx.x & 63;
    const int wv   = threadIdx.x >> 6;
    const int l = lane & 15;
    const int q = lane >> 4;

    // A-frags: A[m = tag mt*16+l][k = q*8+j+32kc] = ThetaB[tag][k]
    bf16x8 Af[4][4];
#pragma unroll
    for (int mt = 0; mt < 4; ++mt)
#pragma unroll
        for (int kc = 0; kc < 4; ++kc) {
            const float4* tp = (const float4*)ThetaB + (mt * 16 + l) * 32 + kc * 8 + q * 2;
            Af[mt][kc] = pack8(tp[0], tp[1]);
        }

    const int base0 = blockIdx.x * 64 + wv * 32;   // 2 tiles of 16 rows per wave

    // load B-frags (E row in native layout) for tile `it`
    auto loadB = [&](int it, float4 (&ef)[8]) {
        int row = base0 + it * 16 + l;
        if (row >= NROWS) row = NROWS - 1;
        const float4* ep = (const float4*)E + (size_t)row * 32 + q * 2;
#pragma unroll
        for (int kc = 0; kc < 4; ++kc) {
            ef[2 * kc]     = ep[kc * 8];
            ef[2 * kc + 1] = ep[kc * 8 + 1];
        }
    };

    float4 cur[8], nxt[8];
    loadB(0, cur);

#pragma unroll
    for (int it = 0; it < 2; ++it) {
        if (it == 0) loadB(1, nxt);              // prefetch next tile's E rows

        bf16x8 Bf[4];
#pragma unroll
        for (int kc = 0; kc < 4; ++kc)
            Bf[kc] = pack8(cur[2 * kc], cur[2 * kc + 1]);

        f32x4 D[4];
#pragma unroll
        for (int mt = 0; mt < 4; ++mt) { f32x4 z = {0.f, 0.f, 0.f, 0.f}; D[mt] = z; }
#pragma unroll
        for (int kc = 0; kc < 4; ++kc)
#pragma unroll
            for (int mt = 0; mt < 4; ++mt)
                D[mt] = __builtin_amdgcn_mfma_f32_16x16x32_bf16(Af[mt][kc], Bf[kc], D[mt], 0, 0, 0);

        const int row = base0 + it * 16 + l;     // D[mt][r] = tag mt*16+q*4+r, word row
        if (row < NROWS) {
#pragma unroll
            for (int mt = 0; mt < 4; ++mt) {
                float v0 = expf(D[mt][0]), v1 = expf(D[mt][1]);
                float v2 = expf(D[mt][2]), v3 = expf(D[mt][3]);
                if (mt == 3 && q == 3) { v2 = 0.f; v3 = 0.f; }   // tags 62, 63
                uint2 o; o.x = pack_bf2(v0, v1); o.y = pack_bf2(v2, v3);
                Btb[BIDX(row, q, mt)] = o;       // permuted layout
            }
        }
#pragma unroll
        for (int d = 0; d < 8; ++d) cur[d] = nxt[d];
    }
}

// ---------------------------------------------------------------------------
// Kernel 2: fwd/bwd recurrence, in-register MFMA steps (no LDS per step).
// State X = B-operand: X[tag = kc*16+q*4+j][sent = l], bf16x4 per kc.
// fwd (wv=0): A = S^T, X' = (S^T X) o e_t, t up;  bwd: A = S, X' = e o (S X).
// Emission ring: 6 steps deep, each entry = 2 uint4 (one contiguous 32 B
// dwordx4 pair). Words fetched 8 steps ahead (scalar, L1-warm).
// ---------------------------------------------------------------------------
__global__ __launch_bounds__(128, 1) void crf_fwdbwd(
    const int* __restrict__ words, const float* __restrict__ WA,
    const uint2* __restrict__ Btb, float* __restrict__ out)
{
    __shared__ float ytile[16 * 68];
    const int lane  = threadIdx.x & 63;
    const int wv    = threadIdx.x >> 6;          // 0 = fwd, 1 = bwd
    const int l     = lane & 15;
    const int q     = lane >> 4;
    const int sbase = blockIdx.x * 16;

    // Transition A-frags. S[i][j] = exp(WA[i][j]) * (j != BOS)/64.
    bf16x4 Sf[4][4];
#pragma unroll
    for (int mt = 0; mt < 4; ++mt)
#pragma unroll
        for (int kc = 0; kc < 4; ++kc) {
            float t[4];
#pragma unroll
            for (int j = 0; j < 4; ++j) {
                const int mg = mt * 16 + l;
                const int kg = kc * 16 + q * 4 + j;
                const int ii = wv ? mg : kg;
                const int jj = wv ? kg : mg;
                t[j] = (jj == BOS_T) ? 0.f : expf(WA[ii * 64 + jj]) * 0.015625f;
            }
            Sf[mt][kc] = pack4(t[0], t[1], t[2], t[3]);
        }

    // Init vector, tag jt = kc*16+q*4+e: fwd S[BOS][jt]; bwd S[jt][EOS].
    float g[4][4];
#pragma unroll
    for (int kc = 0; kc < 4; ++kc)
#pragma unroll
        for (int e = 0; e < 4; ++e) {
            const int jt = kc * 16 + q * 4 + e;
            g[kc][e] = wv ? expf(WA[jt * 64 + EOS_T]) * 0.015625f
                          : ((jt == BOS_T) ? 0.f : expf(WA[BOS_T * 64 + jt]) * 0.015625f);
        }

    const int wb   = (sbase + l) * TLEN;
    const int tdir = wv ? -1 : 1;
    const int t0   = wv ? 254 : 1;

    auto eload = [&](int w, uint4& lo, uint4& hi) {
        const uint4* p = (const uint4*)(Btb + BIDX(w, q, 0));
        lo = p[0]; hi = p[1];                    // kc 0,1 | kc 2,3
    };

    uint4 eiL, eiH, eAL, eAH, eBL, eBH, eCL, eCH, eDL, eDH, eEL, eEH, eFL, eFH;
    eload(words[wb + t0], eiL, eiH);
    eload(words[wb + t0 + 1 * tdir], eAL, eAH);  // emis for substep 0
    eload(words[wb + t0 + 2 * tdir], eBL, eBH);
    eload(words[wb + t0 + 3 * tdir], eCL, eCH);
    eload(words[wb + t0 + 4 * tdir], eDL, eDH);
    eload(words[wb + t0 + 5 * tdir], eEL, eEH);
    eload(words[wb + t0 + 6 * tdir], eFL, eFH);  // emis for substep 5
    int wdA = words[wb + t0 + 7 * tdir];         // word for substep 6
    int wdB = words[wb + t0 + 8 * tdir];
    int wdC = words[wb + t0 + 9 * tdir];
    int wdD = words[wb + t0 + 10 * tdir];
    int wdE = words[wb + t0 + 11 * tdir];
    int wdF = words[wb + t0 + 12 * tdir];        // word for substep 11

    // X init = g o e_{t0}
    bf16x4 X[4];
    {
        unsigned u[4] = {0, 0, 0, 0};
        u[0] = eiL.x; u[1] = eiL.z; u[2] = eiH.x; u[3] = eiH.z;
        unsigned v[4]; v[0] = eiL.y; v[1] = eiL.w; v[2] = eiH.y; v[3] = eiH.w;
#pragma unroll
        for (int kc = 0; kc < 4; ++kc) {
            float f0 = __uint_as_float(u[kc] << 16)         * g[kc][0];
            float f1 = __uint_as_float(u[kc] & 0xffff0000u) * g[kc][1];
            float f2 = __uint_as_float(v[kc] << 16)         * g[kc][2];
            float f3 = __uint_as_float(v[kc] & 0xffff0000u) * g[kc][3];
            X[kc] = pack4(f0, f1, f2, f3);
        }
    }

    float xf[4][4];                              // last step's f32 state (join)

    // substep consuming step i: refills (lo,hi) for step i+6, fetches word i+12
    auto substep = [&](uint4& lo, uint4& hi, int& wd, int widx) {
        f32x4 D[4];
#pragma unroll
        for (int mt = 0; mt < 4; ++mt) { f32x4 z = {0.f, 0.f, 0.f, 0.f}; D[mt] = z; }
#pragma unroll
        for (int kc = 0; kc < 4; ++kc)
#pragma unroll
            for (int mt = 0; mt < 4; ++mt)
                D[mt] = __builtin_amdgcn_mfma_f32_16x16x16bf16_1k(Sf[mt][kc], X[kc], D[mt], 0, 0, 0);
        unsigned u[4], v[4];
        u[0] = lo.x; v[0] = lo.y; u[1] = lo.z; v[1] = lo.w;
        u[2] = hi.x; v[2] = hi.y; u[3] = hi.z; v[3] = hi.w;
#pragma unroll
        for (int kc = 0; kc < 4; ++kc) {
            float f0 = __uint_as_float(u[kc] << 16);
            float f1 = __uint_as_float(u[kc] & 0xffff0000u);
            float f2 = __uint_as_float(v[kc] << 16);
            float f3 = __uint_as_float(v[kc] & 0xffff0000u);
            xf[kc][0] = D[kc][0] * f0;  xf[kc][1] = D[kc][1] * f1;
            xf[kc][2] = D[kc][2] * f2;  xf[kc][3] = D[kc][3] * f3;
            X[kc] = pack4(xf[kc][0], xf[kc][1], xf[kc][2], xf[kc][3]);
        }
        eload(wd, lo, hi);
        wd = words[wb + widx];
    };

    // 126 substeps; word idx bounds: fwd max 1+138=139 < 256, bwd min 254-138 >= 0
    for (int i = 0; i < 126; i += 6) {
        substep(eAL, eAH, wdA, t0 + tdir * (i + 13));
        substep(eBL, eBH, wdB, t0 + tdir * (i + 14));
        substep(eCL, eCH, wdC, t0 + tdir * (i + 15));
        substep(eDL, eDH, wdD, t0 + tdir * (i + 16));
        substep(eEL, eEH, wdE, t0 + tdir * (i + 17));
        substep(eFL, eFH, wdF, t0 + tdir * (i + 18));
    }

    if (wv == 0) {
        // extra step: Y = S^T alpha_127 (no emission) -> LDS
        f32x4 D[4];
#pragma unroll
        for (int mt = 0; mt < 4; ++mt) { f32x4 z = {0.f, 0.f, 0.f, 0.f}; D[mt] = z; }
#pragma unroll
        for (int kc = 0; kc < 4; ++kc)
#pragma unroll
            for (int mt = 0; mt < 4; ++mt)
                D[mt] = __builtin_amdgcn_mfma_f32_16x16x16bf16_1k(Sf[mt][kc], X[kc], D[mt], 0, 0, 0);
#pragma unroll
        for (int mt = 0; mt < 4; ++mt) {
            float4 o = {D[mt][0], D[mt][1], D[mt][2], D[mt][3]};
            *(float4*)&ytile[l * 68 + mt * 16 + q * 4] = o;
        }
    }
    __syncthreads();
    if (wv == 1) {
        // z[s] = sum_tag Y[tag][s] * (e_128 o q_128)[tag][s]
        float p = 0.f;
#pragma unroll
        for (int mt = 0; mt < 4; ++mt)
#pragma unroll
            for (int r = 0; r < 4; ++r)
                p = fmaf(ytile[l * 68 + mt * 16 + q * 4 + r], xf[mt][r], p);
        p += __shfl_xor(p, 16, 64);
        p += __shfl_xor(p, 32, 64);
        if (lane < 16)
            out[sbase + l] = logf(p) + 255.0f * LOG64;
    }
}

extern "C" void kernel_launch(void* const* d_in, const int* in_sizes, int n_in,
                              void* d_out, int out_size, void* d_ws, size_t ws_size,
                              hipStream_t stream) {
    const int*   words  = (const int*)d_in[0];
    const float* ThetaB = (const float*)d_in[1];
    const float* WA     = (const float*)d_in[2];
    const float* E      = (const float*)d_in[3];
    float*       outp   = (float*)d_out;
    uint2*       Btb    = (uint2*)d_ws;          // 50002*128 B = 6.4 MB

    // 782 blocks x 2 waves x 2 tiles x 16 rows = 50048 >= 50002
    emis_mfma<<<dim3(782), dim3(128), 0, stream>>>(ThetaB, E, Btb);
    // 128 blocks x (fwd wave + bwd wave), 16 sentences each
    crf_fwdbwd<<<dim3(128), dim3(128), 0, stream>>>(words, WA, Btb, outp);
}